// Round 4
// baseline (616.360 us; speedup 1.0000x reference)
//
#include <hip/hip_runtime.h>

#define HNEG (-1000000000.0f)

constexpr int Nc = 128;
constexpr int Mc = 128;
constexpr int CELLS = Nc * Mc * 3;  // 49152 floats per batch

__device__ __forceinline__ float lse3(float a, float b, float c) {
  float mx = fmaxf(fmaxf(a, b), c);
  return mx + __logf(__expf(a - mx) + __expf(b - mx) + __expf(c - mx));
}

// ---------------------------------------------------------------------------
// Fused wavefront kernel: one wave (64 lanes) per batch. Lane l owns columns
// 2l, 2l+1 of BOTH the forward lattice (alpha) and the flipped backward
// lattice (u = g + theta_f). The two recurrences are independent chains ->
// ILP. alpha is written to ws (raw), g (= beta) to d_out (raw); a separate
// coalesced kernel computes out = alpha + g - logZ.
// Q layout per diagonal u: [0..2] theta fwd even col, [3..5] theta fwd odd,
// [6..8] theta bwd even col, [9..11] theta bwd odd.
// ---------------------------------------------------------------------------
__device__ __forceinline__ void loadQ(const float* __restrict__ th, int d0,
                                      int l, float (&Q)[4][12]) {
  const int jA = 2 * l, jB = 2 * l + 1;
  const int jjA = Mc - 1 - jA, jjB = Mc - 1 - jB;
#pragma unroll
  for (int u = 0; u < 4; ++u) {
    const int d = d0 + u;
    const int iA = d - jA, iB = d - jB;        // fwd rows
    const int pA = Nc - 1 - d + jA;            // bwd row, even col (q = jA)
    const int pB = Nc - 1 - d + jB;            // bwd row, odd col  (q = jB)
    if (iA >= 0 && iA < Nc) {
      const float3 v = *reinterpret_cast<const float3*>(th + (iA * Mc + jA) * 3);
      Q[u][0] = v.x; Q[u][1] = v.y; Q[u][2] = v.z;
    } else { Q[u][0] = Q[u][1] = Q[u][2] = 0.f; }
    if (iB >= 0 && iB < Nc) {
      const float3 v = *reinterpret_cast<const float3*>(th + (iB * Mc + jB) * 3);
      Q[u][3] = v.x; Q[u][4] = v.y; Q[u][5] = v.z;
    } else { Q[u][3] = Q[u][4] = Q[u][5] = 0.f; }
    if (pA >= 0 && pA < Nc) {
      const float3 v = *reinterpret_cast<const float3*>(th + (pA * Mc + jjA) * 3);
      Q[u][6] = v.x; Q[u][7] = v.y; Q[u][8] = v.z;
    } else { Q[u][6] = Q[u][7] = Q[u][8] = 0.f; }
    if (pB >= 0 && pB < Nc) {
      const float3 v = *reinterpret_cast<const float3*>(th + (pB * Mc + jjB) * 3);
      Q[u][9] = v.x; Q[u][10] = v.y; Q[u][11] = v.z;
    } else { Q[u][9] = Q[u][10] = Q[u][11] = 0.f; }
  }
}

__global__ __launch_bounds__(64, 1) void fused_kernel(
    const float* __restrict__ theta, const float* __restrict__ A,
    float* __restrict__ alpha_ws, float* __restrict__ g_out,
    float* __restrict__ logZ_ws) {
  const int b = blockIdx.x;
  const int l = threadIdx.x;
  const float* th = theta + (size_t)b * CELLS;
  float* oa = alpha_ws + (size_t)b * CELLS;
  float* og = g_out + (size_t)b * CELLS;
  const float* Ab = A + b * 9;

  float Ae[3][3];  // Ae[k][s] = e^{A[k,s]}  (fwd consumes column s)
  float Er[3][3];  // Er[s][k] = e^{A[s,k]}  (bwd consumes row s)
#pragma unroll
  for (int r = 0; r < 3; ++r)
#pragma unroll
    for (int c = 0; c < 3; ++c) {
      const float a = Ab[r * 3 + c];
      Ae[r][c] = __expf(a);   // row r = k, col c = s
      Er[r][c] = __expf(a);   // row r = s, col c = k (same storage, same value)
    }

  const int jA = 2 * l, jB = 2 * l + 1;
  const int jjA = Mc - 1 - jA, jjB = Mc - 1 - jB;

  // ---- fwd state (exp-published): (m, w_k = e^{c_k - m}) ----
  float mPA = HNEG, wPA0 = 1.f, wPA1 = 1.f, wPA2 = 1.f;  // own even @ d-1
  float mPB = HNEG, wPB0 = 1.f, wPB1 = 1.f, wPB2 = 1.f;  // own odd  @ d-1
  float mPP = HNEG, wPP0 = 1.f, wPP1 = 1.f, wPP2 = 1.f;  // own even @ d-2
  float mS1 = HNEG, wS10 = 1.f, wS11 = 1.f, wS12 = 1.f;  // nbr odd  @ d-1
  float mS2 = HNEG, wS20 = 1.f, wS21 = 1.f, wS22 = 1.f;  // nbr odd  @ d-2
  // ---- bwd state (plain u values) ----
  float pAu0 = HNEG, pAu1 = HNEG, pAu2 = HNEG;  // own even u @ d-1
  float ppAu0 = HNEG;                           // own even u0 @ d-2
  float pBu1 = HNEG;                            // own odd u1 @ d-1
  float S1u0 = HNEG, S1u2 = HNEG, S2u0 = HNEG;  // nbr odd u @ d-1 / u0 @ d-2
  // alpha(127,127,:) capture for logZ (valid in lane 63)
  float fz0 = HNEG, fz1 = HNEG, fz2 = HNEG;

  float Qa[4][12], Qb[4][12];
  loadQ(th, 0, l, Qa);
  loadQ(th, 4, l, Qb);

  auto step = [&](float(&Q)[4][12], int d0) {
#pragma unroll
    for (int u = 0; u < 4; ++u) {
      const int d = d0 + u;
      // ================= forward chain =================
      {
        const int iA = d - jA, iB = d - jB;
        float g0 = mS2 + __logf(wS20 * Ae[0][0] + wS21 * Ae[1][0] + wS22 * Ae[2][0]);
        float g1 = mPA + __logf(wPA0 * Ae[0][1] + wPA1 * Ae[1][1] + wPA2 * Ae[2][1]);
        float g2 = mS1 + __logf(wS10 * Ae[0][2] + wS11 * Ae[1][2] + wS12 * Ae[2][2]);
        if (d == 0 && l == 0) g0 = 0.0f;  // origin: lse_m := 0 at (0,0)
        float cA0 = HNEG, cA1 = HNEG, cA2 = HNEG;
        if (iA >= 0 && iA < Nc) {
          cA0 = Q[u][0] + g0; cA1 = Q[u][1] + g1; cA2 = Q[u][2] + g2;
          *reinterpret_cast<float3*>(oa + (iA * Mc + jA) * 3) =
              make_float3(cA0, cA1, cA2);
        }
        float h0 = mPP + __logf(wPP0 * Ae[0][0] + wPP1 * Ae[1][0] + wPP2 * Ae[2][0]);
        float h1 = mPB + __logf(wPB0 * Ae[0][1] + wPB1 * Ae[1][1] + wPB2 * Ae[2][1]);
        float h2 = mPA + __logf(wPA0 * Ae[0][2] + wPA1 * Ae[1][2] + wPA2 * Ae[2][2]);
        float cB0 = HNEG, cB1 = HNEG, cB2 = HNEG;
        if (iB >= 0 && iB < Nc) {
          cB0 = Q[u][3] + h0; cB1 = Q[u][4] + h1; cB2 = Q[u][5] + h2;
          *reinterpret_cast<float3*>(oa + (iB * Mc + jB) * 3) =
              make_float3(cB0, cB1, cB2);
        }
        if (d == Nc + Mc - 2) { fz0 = cB0; fz1 = cB1; fz2 = cB2; }  // (127,127)
        const float mA = fmaxf(fmaxf(cA0, cA1), cA2);
        const float a0 = __expf(cA0 - mA), a1 = __expf(cA1 - mA), a2 = __expf(cA2 - mA);
        const float mB = fmaxf(fmaxf(cB0, cB1), cB2);
        const float b0 = __expf(cB0 - mB), b1 = __expf(cB1 - mB), b2 = __expf(cB2 - mB);
        mPP = mPA; wPP0 = wPA0; wPP1 = wPA1; wPP2 = wPA2;
        mPA = mA;  wPA0 = a0;   wPA1 = a1;   wPA2 = a2;
        mPB = mB;  wPB0 = b0;   wPB1 = b1;   wPB2 = b2;
        mS2 = mS1; wS20 = wS10; wS21 = wS11; wS22 = wS12;
        mS1 = __shfl_up(mB, 1);
        wS10 = __shfl_up(b0, 1); wS11 = __shfl_up(b1, 1); wS12 = __shfl_up(b2, 1);
        if (l == 0) { mS1 = HNEG; wS10 = wS11 = wS12 = 1.f; }
      }
      // ================= backward chain =================
      {
        const int iA = Nc - 1 - d + jA;  // orig row, even col (q = jA)
        const int iB = Nc - 1 - d + jB;  // orig row, odd col  (q = jB)
        // even column: v = [nbr-odd u0 @d-2, own-even u1 @d-1, nbr-odd u2 @d-1]
        float uA0 = HNEG, uA1 = HNEG, uA2 = HNEG;
        {
          const float v0 = S2u0, v1 = pAu1, v2 = S1u2;
          const float mv = fmaxf(fmaxf(v0, v1), v2);
          const float w0 = __expf(v0 - mv), w1 = __expf(v1 - mv), w2 = __expf(v2 - mv);
          float g0 = mv + __logf(w0 * Er[0][0] + w1 * Er[0][1] + w2 * Er[0][2]);
          float g1 = mv + __logf(w0 * Er[1][0] + w1 * Er[1][1] + w2 * Er[1][2]);
          float g2 = mv + __logf(w0 * Er[2][0] + w1 * Er[2][1] + w2 * Er[2][2]);
          if (d == 0 && l == 0) { g0 = 0.f; g1 = 0.f; g2 = 0.f; }  // beta(end)=0
          if (iA >= 0 && iA < Nc) {
            uA0 = g0 + Q[u][6]; uA1 = g1 + Q[u][7]; uA2 = g2 + Q[u][8];
            *reinterpret_cast<float3*>(og + (iA * Mc + jjA) * 3) =
                make_float3(g0, g1, g2);
          }
        }
        // odd column: v = [own-even u0 @d-2, own-odd u1 @d-1, own-even u2 @d-1]
        float uB0 = HNEG, uB1 = HNEG, uB2 = HNEG;
        {
          const float v0 = ppAu0, v1 = pBu1, v2 = pAu2;
          const float mv = fmaxf(fmaxf(v0, v1), v2);
          const float w0 = __expf(v0 - mv), w1 = __expf(v1 - mv), w2 = __expf(v2 - mv);
          const float g0 = mv + __logf(w0 * Er[0][0] + w1 * Er[0][1] + w2 * Er[0][2]);
          const float g1 = mv + __logf(w0 * Er[1][0] + w1 * Er[1][1] + w2 * Er[1][2]);
          const float g2 = mv + __logf(w0 * Er[2][0] + w1 * Er[2][1] + w2 * Er[2][2]);
          if (iB >= 0 && iB < Nc) {
            uB0 = g0 + Q[u][9]; uB1 = g1 + Q[u][10]; uB2 = g2 + Q[u][11];
            *reinterpret_cast<float3*>(og + (iB * Mc + jjB) * 3) =
                make_float3(g0, g1, g2);
          }
        }
        ppAu0 = pAu0; pAu0 = uA0; pAu1 = uA1; pAu2 = uA2; pBu1 = uB1;
        S2u0 = S1u0;
        S1u0 = __shfl_up(uB0, 1);
        S1u2 = __shfl_up(uB2, 1);
        if (l == 0) { S1u0 = HNEG; S1u2 = HNEG; }
      }
    }
  };

  for (int t = 0; t < 64; t += 2) {
    step(Qa, 4 * t);
    loadQ(th, 4 * t + 8, l, Qa);
    step(Qb, 4 * t + 4);
    loadQ(th, 4 * t + 12, l, Qb);
  }

  if (l == 63) logZ_ws[b] = lse3(fz0, fz1, fz2);
}

// out = alpha(ws) + g(d_out) - logZ[b], coalesced float4, in place on d_out.
__global__ __launch_bounds__(256) void combine_kernel(
    const float* __restrict__ aws, const float* __restrict__ zws,
    float* __restrict__ out) {
  const int b = blockIdx.y;
  const int v = blockIdx.x * 256 + threadIdx.x;  // 0..12287 float4s per batch
  const float lz = zws[b];
  const float4* a = reinterpret_cast<const float4*>(aws + (size_t)b * CELLS);
  float4* o = reinterpret_cast<float4*>(out + (size_t)b * CELLS);
  const float4 va = a[v];
  const float4 vg = o[v];
  o[v] = make_float4(va.x + vg.x - lz, va.y + vg.y - lz,
                     va.z + vg.z - lz, va.w + vg.w - lz);
}

// ---------------------------------------------------------------------------
// Fallback (round-2, known-correct, ~355 us): used only if ws is too small.
// ---------------------------------------------------------------------------
__global__ __launch_bounds__(128) void fwd_fb(const float* __restrict__ theta,
                                              const float* __restrict__ A,
                                              float* __restrict__ out) {
  const int b = blockIdx.x;
  const int j = threadIdx.x;
  const float* th = theta + (size_t)b * CELLS;
  float* ob = out + (size_t)b * CELLS;

  __shared__ float sA[9];
  __shared__ float ring[3][Mc + 1][3];
  if (j < 9) sA[j] = A[b * 9 + j];
  {
    float* rf = &ring[0][0][0];
    for (int t = j; t < 3 * (Mc + 1) * 3; t += Mc) rf[t] = HNEG;
  }
  __syncthreads();
  const float A00 = sA[0], A01 = sA[1], A02 = sA[2];
  const float A10 = sA[3], A11 = sA[4], A12 = sA[5];
  const float A20 = sA[6], A21 = sA[7], A22 = sA[8];

  float p0 = HNEG, p1 = HNEG, p2 = HNEG;
  float tc0 = 0.f, tc1 = 0.f, tc2 = 0.f, tn0 = 0.f, tn1 = 0.f, tn2 = 0.f;
  if (j == 0) { tc0 = th[0]; tc1 = th[1]; tc2 = th[2]; }
  if (j <= 1) {
    const int i1 = 1 - j;
    const float* p = th + (i1 * Mc + j) * 3;
    tn0 = p[0]; tn1 = p[1]; tn2 = p[2];
  }
  int s0 = 0, s1 = 2, s2 = 1;
  for (int d = 0; d < Nc + Mc - 1; ++d) {
    const int i = d - j;
    float tf0 = 0.f, tf1 = 0.f, tf2 = 0.f;
    const int ip = i + 2;
    if (ip >= 0 && ip < Nc) {
      const float* p = th + (ip * Mc + j) * 3;
      tf0 = p[0]; tf1 = p[1]; tf2 = p[2];
    }
    float c0 = HNEG, c1 = HNEG, c2 = HNEG;
    if (i >= 0 && i < Nc) {
      const float* nd1 = ring[s1][j];
      const float* nd2 = ring[s2][j];
      float lm = lse3(nd2[0] + A00, nd2[1] + A10, nd2[2] + A20);
      if (i == 0 && j == 0) lm = 0.0f;
      float lx = lse3(p0 + A01, p1 + A11, p2 + A21);
      float ly = lse3(nd1[0] + A02, nd1[1] + A12, nd1[2] + A22);
      c0 = tc0 + lm; c1 = tc1 + lx; c2 = tc2 + ly;
      float* o = ob + (i * Mc + j) * 3;
      o[0] = c0; o[1] = c1; o[2] = c2;
    }
    float* w = ring[s0][j + 1];
    w[0] = c0; w[1] = c1; w[2] = c2;
    __syncthreads();
    p0 = c0; p1 = c1; p2 = c2;
    tc0 = tn0; tc1 = tn1; tc2 = tn2;
    tn0 = tf0; tn1 = tf1; tn2 = tf2;
    const int t = s2; s2 = s1; s1 = s0; s0 = t;
  }
}

__global__ __launch_bounds__(128) void bwd_fb(const float* __restrict__ theta,
                                              const float* __restrict__ A,
                                              float* __restrict__ ob_) {
  const int b = blockIdx.x;
  const int q = threadIdx.x;
  const float* th = theta + (size_t)b * CELLS;
  float* ob = ob_ + (size_t)b * CELLS;

  __shared__ float sA[9];
  __shared__ float ring[3][Mc + 1][3];
  __shared__ float sZ;
  if (q < 9) sA[q] = A[b * 9 + q];
  {
    float* rf = &ring[0][0][0];
    for (int t = q; t < 3 * (Mc + 1) * 3; t += Mc) rf[t] = HNEG;
  }
  if (q == 0) {
    sZ = lse3(ob[(Nc * Mc - 1) * 3 + 0], ob[(Nc * Mc - 1) * 3 + 1],
              ob[(Nc * Mc - 1) * 3 + 2]);
  }
  __syncthreads();
  const float A00 = sA[0], A01 = sA[1], A02 = sA[2];
  const float A10 = sA[3], A11 = sA[4], A12 = sA[5];
  const float A20 = sA[6], A21 = sA[7], A22 = sA[8];
  const float logZ = sZ;

  const int jj = Mc - 1 - q;
  float pu1 = HNEG;
  float tc0 = 0.f, tc1 = 0.f, tc2 = 0.f, tn0 = 0.f, tn1 = 0.f, tn2 = 0.f;
  float ac0 = 0.f, ac1 = 0.f, ac2 = 0.f, an0 = 0.f, an1 = 0.f, an2 = 0.f;
  if (q == 0) {
    const float* p = th + ((Nc - 1) * Mc + jj) * 3;
    tc0 = p[0]; tc1 = p[1]; tc2 = p[2];
    const float* a = ob + ((Nc - 1) * Mc + jj) * 3;
    ac0 = a[0]; ac1 = a[1]; ac2 = a[2];
  }
  if (q <= 1) {
    const int i1 = Nc - 2 + q;
    const float* p = th + (i1 * Mc + jj) * 3;
    tn0 = p[0]; tn1 = p[1]; tn2 = p[2];
    const float* a = ob + (i1 * Mc + jj) * 3;
    an0 = a[0]; an1 = a[1]; an2 = a[2];
  }
  int s0 = 0, s1 = 2, s2 = 1;
  for (int d = 0; d < Nc + Mc - 1; ++d) {
    const int p = d - q;
    const int i = Nc - 1 - p;
    float tf0 = 0.f, tf1 = 0.f, tf2 = 0.f, af0 = 0.f, af1 = 0.f, af2 = 0.f;
    const int ipf = i - 2;
    if (ipf >= 0 && ipf < Nc) {
      const float* pp = th + (ipf * Mc + jj) * 3;
      tf0 = pp[0]; tf1 = pp[1]; tf2 = pp[2];
      const float* aa = ob + (ipf * Mc + jj) * 3;
      af0 = aa[0]; af1 = aa[1]; af2 = aa[2];
    }
    float u0 = HNEG, u1 = HNEG, u2 = HNEG;
    if (p >= 0 && p < Nc) {
      const float* nd1 = ring[s1][q];
      const float* nd2 = ring[s2][q];
      const float v0 = nd2[0];
      const float v1 = pu1;
      const float v2 = nd1[2];
      float g0 = lse3(A00 + v0, A01 + v1, A02 + v2);
      float g1 = lse3(A10 + v0, A11 + v1, A12 + v2);
      float g2 = lse3(A20 + v0, A21 + v1, A22 + v2);
      if (p == 0 && q == 0) { g0 = 0.0f; g1 = 0.0f; g2 = 0.0f; }
      u0 = g0 + tc0; u1 = g1 + tc1; u2 = g2 + tc2;
      float* o = ob + (i * Mc + jj) * 3;
      o[0] = ac0 + g0 - logZ;
      o[1] = ac1 + g1 - logZ;
      o[2] = ac2 + g2 - logZ;
    }
    float* w = ring[s0][q + 1];
    w[0] = u0; w[1] = u1; w[2] = u2;
    __syncthreads();
    pu1 = u1;
    tc0 = tn0; tc1 = tn1; tc2 = tn2;
    tn0 = tf0; tn1 = tf1; tn2 = tf2;
    ac0 = an0; ac1 = an1; ac2 = an2;
    an0 = af0; an1 = af1; an2 = af2;
    const int t = s2; s2 = s1; s1 = s0; s0 = t;
  }
}

extern "C" void kernel_launch(void* const* d_in, const int* in_sizes, int n_in,
                              void* d_out, int out_size, void* d_ws, size_t ws_size,
                              hipStream_t stream) {
  const float* theta = (const float*)d_in[0];
  const float* A = (const float*)d_in[1];
  float* out = (float*)d_out;
  const int B = in_sizes[1] / 9;  // A is (B, 3, 3)

  const size_t need = (size_t)B * CELLS * sizeof(float) + (size_t)B * sizeof(float);
  if (ws_size >= need) {
    float* alpha_ws = (float*)d_ws;
    float* logZ_ws = alpha_ws + (size_t)B * CELLS;
    fused_kernel<<<dim3(B), dim3(64), 0, stream>>>(theta, A, alpha_ws, out, logZ_ws);
    combine_kernel<<<dim3(CELLS / 4 / 256, B), dim3(256), 0, stream>>>(
        alpha_ws, logZ_ws, out);
  } else {
    fwd_fb<<<dim3(B), dim3(128), 0, stream>>>(theta, A, out);
    bwd_fb<<<dim3(B), dim3(128), 0, stream>>>(theta, A, out);
  }
}

// Round 5
// 494.333 us; speedup vs baseline: 1.2469x; 1.2469x over previous
//
#include <hip/hip_runtime.h>

#define HNEG (-1000000000.0f)

constexpr int Nc = 128;
constexpr int Mc = 128;
constexpr int CELLS = Nc * Mc * 3;

__device__ __forceinline__ float lse3(float a, float b, float c) {
  float mx = fmaxf(fmaxf(a, b), c);
  return mx + __logf(__expf(a - mx) + __expf(b - mx) + __expf(c - mx));
}

// 6 named scalars per pipeline slot (2 cols x 3 states)
#define DECL6(p) float p##0, p##1, p##2, p##3, p##4, p##5

// ---------------------------------------------------------------------------
// Forward kernel: one wave per batch, lane l owns columns jA=2l, jB=2l+1.
// Exp-published cells: (m, w_k = e^{c_k - m}); consumer computes
// LSE_k(c_k + A[k,s]) = m + log(sum_k w_k * E[k][s]).  E[r][c] = e^{A[r][c]}.
// Neighbor (col-1) odd-column cells arrive via __shfl_up — no barriers.
// Software pipeline: two scalar banks (xt*, yt*), loads issued 4 diagonals
// ahead of use, no bank-to-bank copies.
// ---------------------------------------------------------------------------

#define FLOADS(P, dd) do {                                                     \
    const int iA_ = (dd) - jA, iB_ = (dd) - jB;                                \
    if ((unsigned)iA_ < (unsigned)Nc) {                                        \
      const float* p_ = th + (iA_ * Mc + jA) * 3;                              \
      P##0 = p_[0]; P##1 = p_[1]; P##2 = p_[2];                                \
    } else { P##0 = 0.f; P##1 = 0.f; P##2 = 0.f; }                             \
    if ((unsigned)iB_ < (unsigned)Nc) {                                        \
      const float* p_ = th + (iB_ * Mc + jB) * 3;                              \
      P##3 = p_[0]; P##4 = p_[1]; P##5 = p_[2];                                \
    } else { P##3 = 0.f; P##4 = 0.f; P##5 = 0.f; }                             \
  } while (0)

#define FSTEP(P, dd) do {                                                      \
    const int iA_ = (dd) - jA, iB_ = (dd) - jB;                                \
    float g0 = mS2 + __logf(wS20 * E00 + wS21 * E10 + wS22 * E20);             \
    float g1 = mPA + __logf(wPA0 * E01 + wPA1 * E11 + wPA2 * E21);             \
    float g2 = mS1 + __logf(wS10 * E02 + wS11 * E12 + wS12 * E22);             \
    if ((dd) == 0 && l == 0) g0 = 0.0f; /* origin: lse_m := 0 at (0,0) */      \
    float cA0 = HNEG, cA1 = HNEG, cA2 = HNEG;                                  \
    if ((unsigned)iA_ < (unsigned)Nc) {                                        \
      cA0 = P##0 + g0; cA1 = P##1 + g1; cA2 = P##2 + g2;                       \
      float* o_ = ob + (iA_ * Mc + jA) * 3;                                    \
      o_[0] = cA0; o_[1] = cA1; o_[2] = cA2;                                   \
    }                                                                          \
    float h0 = mPP + __logf(wPP0 * E00 + wPP1 * E10 + wPP2 * E20);             \
    float h1 = mPB + __logf(wPB0 * E01 + wPB1 * E11 + wPB2 * E21);             \
    float h2 = mPA + __logf(wPA0 * E02 + wPA1 * E12 + wPA2 * E22);             \
    float cB0 = HNEG, cB1 = HNEG, cB2 = HNEG;                                  \
    if ((unsigned)iB_ < (unsigned)Nc) {                                        \
      cB0 = P##3 + h0; cB1 = P##4 + h1; cB2 = P##5 + h2;                       \
      float* o_ = ob + (iB_ * Mc + jB) * 3;                                    \
      o_[0] = cB0; o_[1] = cB1; o_[2] = cB2;                                   \
    }                                                                          \
    const float mA_ = fmaxf(fmaxf(cA0, cA1), cA2);                             \
    const float a0_ = __expf(cA0 - mA_), a1_ = __expf(cA1 - mA_),              \
                a2_ = __expf(cA2 - mA_);                                       \
    const float mB_ = fmaxf(fmaxf(cB0, cB1), cB2);                             \
    const float b0_ = __expf(cB0 - mB_), b1_ = __expf(cB1 - mB_),              \
                b2_ = __expf(cB2 - mB_);                                       \
    mPP = mPA; wPP0 = wPA0; wPP1 = wPA1; wPP2 = wPA2;                          \
    mPA = mA_; wPA0 = a0_; wPA1 = a1_; wPA2 = a2_;                             \
    mPB = mB_; wPB0 = b0_; wPB1 = b1_; wPB2 = b2_;                             \
    mS2 = mS1; wS20 = wS10; wS21 = wS11; wS22 = wS12;                          \
    mS1 = __shfl_up(mB_, 1);                                                   \
    wS10 = __shfl_up(b0_, 1); wS11 = __shfl_up(b1_, 1);                        \
    wS12 = __shfl_up(b2_, 1);                                                  \
    if (l == 0) { mS1 = HNEG; wS10 = 1.f; wS11 = 1.f; wS12 = 1.f; }            \
  } while (0)

__global__ __launch_bounds__(64, 1) void fwd_kernel(
    const float* __restrict__ theta, const float* __restrict__ A,
    float* __restrict__ out) {
  const int b = blockIdx.x;
  const int l = threadIdx.x;
  const float* th = theta + (size_t)b * CELLS;
  float* ob = out + (size_t)b * CELLS;
  const float* Ab = A + b * 9;
  const float E00 = __expf(Ab[0]), E01 = __expf(Ab[1]), E02 = __expf(Ab[2]);
  const float E10 = __expf(Ab[3]), E11 = __expf(Ab[4]), E12 = __expf(Ab[5]);
  const float E20 = __expf(Ab[6]), E21 = __expf(Ab[7]), E22 = __expf(Ab[8]);

  const int jA = 2 * l, jB = 2 * l + 1;

  // published state (exp form): own even @d-1 (PA), own even @d-2 (PP),
  // own odd @d-1 (PB), neighbor odd @d-1 (S1), neighbor odd @d-2 (S2)
  float mPA = HNEG, wPA0 = 1.f, wPA1 = 1.f, wPA2 = 1.f;
  float mPB = HNEG, wPB0 = 1.f, wPB1 = 1.f, wPB2 = 1.f;
  float mPP = HNEG, wPP0 = 1.f, wPP1 = 1.f, wPP2 = 1.f;
  float mS1 = HNEG, wS10 = 1.f, wS11 = 1.f, wS12 = 1.f;
  float mS2 = HNEG, wS20 = 1.f, wS21 = 1.f, wS22 = 1.f;

  DECL6(xt0); DECL6(xt1); DECL6(xt2); DECL6(xt3);
  DECL6(yt0); DECL6(yt1); DECL6(yt2); DECL6(yt3);

  FLOADS(xt0, 0); FLOADS(xt1, 1); FLOADS(xt2, 2); FLOADS(xt3, 3);
  FLOADS(yt0, 4); FLOADS(yt1, 5); FLOADS(yt2, 6); FLOADS(yt3, 7);

  for (int t = 0; t < 32; ++t) {
    const int d0 = 8 * t;
    FSTEP(xt0, d0 + 0); FSTEP(xt1, d0 + 1); FSTEP(xt2, d0 + 2); FSTEP(xt3, d0 + 3);
    FLOADS(xt0, d0 + 8); FLOADS(xt1, d0 + 9); FLOADS(xt2, d0 + 10); FLOADS(xt3, d0 + 11);
    FSTEP(yt0, d0 + 4); FSTEP(yt1, d0 + 5); FSTEP(yt2, d0 + 6); FSTEP(yt3, d0 + 7);
    FLOADS(yt0, d0 + 12); FLOADS(yt1, d0 + 13); FLOADS(yt2, d0 + 14); FLOADS(yt3, d0 + 15);
  }
}

// ---------------------------------------------------------------------------
// Backward kernel on flipped grid (p=N-1-i, q=M-1-j), u = g + theta_f:
//   v = [u(p-1,q-1,0), u(p-1,q,1), u(p,q-1,2)]  (shared across output states)
//   g_s = mv + log(sum_k e^{v_k - mv} * E[s][k]);  g = 0 at flipped origin.
// Lane l owns q = 2l (even, orig col jjA) and 2l+1 (odd, orig col jjB).
// In place: reads alpha from d_out (prefetched, read-before-write, same lane),
// writes alpha + g - logZ.
// ---------------------------------------------------------------------------

#define BLOADS(Pt, Pa, dd) do {                                                \
    const int iA_ = Nc - 1 - (dd) + jA;                                        \
    const int iB_ = Nc - 1 - (dd) + jB;                                        \
    if ((unsigned)iA_ < (unsigned)Nc) {                                        \
      const float* p_ = th + (iA_ * Mc + jjA) * 3;                             \
      Pt##0 = p_[0]; Pt##1 = p_[1]; Pt##2 = p_[2];                             \
      const float* q_ = ob + (iA_ * Mc + jjA) * 3;                             \
      Pa##0 = q_[0]; Pa##1 = q_[1]; Pa##2 = q_[2];                             \
    } else { Pt##0 = 0.f; Pt##1 = 0.f; Pt##2 = 0.f;                            \
             Pa##0 = 0.f; Pa##1 = 0.f; Pa##2 = 0.f; }                          \
    if ((unsigned)iB_ < (unsigned)Nc) {                                        \
      const float* p_ = th + (iB_ * Mc + jjB) * 3;                             \
      Pt##3 = p_[0]; Pt##4 = p_[1]; Pt##5 = p_[2];                             \
      const float* q_ = ob + (iB_ * Mc + jjB) * 3;                             \
      Pa##3 = q_[0]; Pa##4 = q_[1]; Pa##5 = q_[2];                             \
    } else { Pt##3 = 0.f; Pt##4 = 0.f; Pt##5 = 0.f;                            \
             Pa##3 = 0.f; Pa##4 = 0.f; Pa##5 = 0.f; }                          \
  } while (0)

#define BSTEP(Pt, Pa, dd) do {                                                 \
    const int iA_ = Nc - 1 - (dd) + jA;                                        \
    const int iB_ = Nc - 1 - (dd) + jB;                                        \
    float uA0 = HNEG, uA1 = HNEG, uA2 = HNEG;                                  \
    {                                                                          \
      const float v0 = S2u0, v1 = pAu1, v2 = S1u2;                             \
      const float mv = fmaxf(fmaxf(v0, v1), v2);                               \
      const float w0 = __expf(v0 - mv), w1 = __expf(v1 - mv),                  \
                  w2 = __expf(v2 - mv);                                        \
      float g0 = mv + __logf(w0 * E00 + w1 * E01 + w2 * E02);                  \
      float g1 = mv + __logf(w0 * E10 + w1 * E11 + w2 * E12);                  \
      float g2 = mv + __logf(w0 * E20 + w1 * E21 + w2 * E22);                  \
      if ((dd) == 0 && l == 0) { g0 = 0.f; g1 = 0.f; g2 = 0.f; }               \
      if ((unsigned)iA_ < (unsigned)Nc) {                                      \
        uA0 = g0 + Pt##0; uA1 = g1 + Pt##1; uA2 = g2 + Pt##2;                  \
        float* o_ = ob + (iA_ * Mc + jjA) * 3;                                 \
        o_[0] = Pa##0 + g0 - logZ;                                             \
        o_[1] = Pa##1 + g1 - logZ;                                             \
        o_[2] = Pa##2 + g2 - logZ;                                             \
      }                                                                        \
    }                                                                          \
    float uB0 = HNEG, uB1 = HNEG, uB2 = HNEG;                                  \
    {                                                                          \
      const float v0 = ppAu0, v1 = pBu1, v2 = pAu2;                            \
      const float mv = fmaxf(fmaxf(v0, v1), v2);                               \
      const float w0 = __expf(v0 - mv), w1 = __expf(v1 - mv),                  \
                  w2 = __expf(v2 - mv);                                        \
      const float g0 = mv + __logf(w0 * E00 + w1 * E01 + w2 * E02);            \
      const float g1 = mv + __logf(w0 * E10 + w1 * E11 + w2 * E12);            \
      const float g2 = mv + __logf(w0 * E20 + w1 * E21 + w2 * E22);            \
      if ((unsigned)iB_ < (unsigned)Nc) {                                      \
        uB0 = g0 + Pt##3; uB1 = g1 + Pt##4; uB2 = g2 + Pt##5;                  \
        float* o_ = ob + (iB_ * Mc + jjB) * 3;                                 \
        o_[0] = Pa##3 + g0 - logZ;                                             \
        o_[1] = Pa##4 + g1 - logZ;                                             \
        o_[2] = Pa##5 + g2 - logZ;                                             \
      }                                                                        \
    }                                                                          \
    ppAu0 = pAu0; pAu0 = uA0; pAu1 = uA1; pAu2 = uA2; pBu1 = uB1;              \
    S2u0 = S1u0;                                                               \
    S1u0 = __shfl_up(uB0, 1);                                                  \
    S1u2 = __shfl_up(uB2, 1);                                                  \
    if (l == 0) { S1u0 = HNEG; S1u2 = HNEG; }                                  \
  } while (0)

__global__ __launch_bounds__(64, 1) void bwd_kernel(
    const float* __restrict__ theta, const float* __restrict__ A,
    float* __restrict__ ob_) {
  const int b = blockIdx.x;
  const int l = threadIdx.x;
  const float* th = theta + (size_t)b * CELLS;
  float* ob = ob_ + (size_t)b * CELLS;
  const float* Ab = A + b * 9;
  const float E00 = __expf(Ab[0]), E01 = __expf(Ab[1]), E02 = __expf(Ab[2]);
  const float E10 = __expf(Ab[3]), E11 = __expf(Ab[4]), E12 = __expf(Ab[5]);
  const float E20 = __expf(Ab[6]), E21 = __expf(Ab[7]), E22 = __expf(Ab[8]);

  const int jA = 2 * l, jB = 2 * l + 1;         // flipped cols q
  const int jjA = Mc - 1 - jA, jjB = Mc - 1 - jB;  // orig cols

  // logZ: broadcast read of alpha(N-1, M-1, :) — before any store here.
  const float* lastp = ob + (Nc * Mc - 1) * 3;
  const float logZ = lse3(lastp[0], lastp[1], lastp[2]);

  // published u state: own even u0/u1/u2 @d-1, own even u0 @d-2,
  // own odd u1 @d-1, neighbor odd u0/u2 @d-1, neighbor odd u0 @d-2.
  float pAu0 = HNEG, pAu1 = HNEG, pAu2 = HNEG;
  float ppAu0 = HNEG, pBu1 = HNEG;
  float S1u0 = HNEG, S1u2 = HNEG, S2u0 = HNEG;

  DECL6(xt0); DECL6(xt1); DECL6(xt2); DECL6(xt3);
  DECL6(yt0); DECL6(yt1); DECL6(yt2); DECL6(yt3);
  DECL6(xa0); DECL6(xa1); DECL6(xa2); DECL6(xa3);
  DECL6(ya0); DECL6(ya1); DECL6(ya2); DECL6(ya3);

  BLOADS(xt0, xa0, 0); BLOADS(xt1, xa1, 1); BLOADS(xt2, xa2, 2); BLOADS(xt3, xa3, 3);
  BLOADS(yt0, ya0, 4); BLOADS(yt1, ya1, 5); BLOADS(yt2, ya2, 6); BLOADS(yt3, ya3, 7);

  for (int t = 0; t < 32; ++t) {
    const int d0 = 8 * t;
    BSTEP(xt0, xa0, d0 + 0); BSTEP(xt1, xa1, d0 + 1);
    BSTEP(xt2, xa2, d0 + 2); BSTEP(xt3, xa3, d0 + 3);
    BLOADS(xt0, xa0, d0 + 8); BLOADS(xt1, xa1, d0 + 9);
    BLOADS(xt2, xa2, d0 + 10); BLOADS(xt3, xa3, d0 + 11);
    BSTEP(yt0, ya0, d0 + 4); BSTEP(yt1, ya1, d0 + 5);
    BSTEP(yt2, ya2, d0 + 6); BSTEP(yt3, ya3, d0 + 7);
    BLOADS(yt0, ya0, d0 + 12); BLOADS(yt1, ya1, d0 + 13);
    BLOADS(yt2, ya2, d0 + 14); BLOADS(yt3, ya3, d0 + 15);
  }
}

extern "C" void kernel_launch(void* const* d_in, const int* in_sizes, int n_in,
                              void* d_out, int out_size, void* d_ws, size_t ws_size,
                              hipStream_t stream) {
  const float* theta = (const float*)d_in[0];
  const float* A = (const float*)d_in[1];
  float* out = (float*)d_out;
  const int B = in_sizes[1] / 9;  // A is (B, 3, 3)

  fwd_kernel<<<dim3(B), dim3(64), 0, stream>>>(theta, A, out);
  bwd_kernel<<<dim3(B), dim3(64), 0, stream>>>(theta, A, out);
}

// Round 6
// 333.435 us; speedup vs baseline: 1.8485x; 1.4825x over previous
//
#include <hip/hip_runtime.h>

#define HNEG (-1000000000.0f)

constexpr int Nc = 128;
constexpr int Mc = 128;
constexpr int CELLS = Nc * Mc * 3;

__device__ __forceinline__ float lse3(float a, float b, float c) {
  float mx = fmaxf(fmaxf(a, b), c);
  return mx + __logf(__expf(a - mx) + __expf(b - mx) + __expf(c - mx));
}

// Compact diagonal-major layout: diag d (= i+j) holds cells j = lo(d)..hi(d),
// stored at (offd(d) + j - lod(d)) * 3 + s within a batch block of CELLS floats.
__device__ __forceinline__ int lod(int d) { return d > 127 ? d - 127 : 0; }
__device__ __forceinline__ int offd(int d) {
  return d <= 128 ? ((d * (d + 1)) >> 1)
                  : 8256 + (d - 128) * 127 - (((d - 128) * (d - 129)) >> 1);
}

// ---------------------------------------------------------------------------
// K1: theta row-major -> theta_diag (compact diag-major). 64x64 LDS tiles.
// Read coalesced by rows; write coalesced runs along each diagonal segment.
// ---------------------------------------------------------------------------
__global__ __launch_bounds__(256) void transpose_kernel(
    const float* __restrict__ theta, float* __restrict__ thd) {
  const int b = blockIdx.x;
  const int tile = blockIdx.y;  // 0..3
  const int i0 = (tile >> 1) * 64, j0 = (tile & 1) * 64;
  const int t = threadIdx.x;
  __shared__ float lds[64 * 192];
  const float* src = theta + (size_t)b * CELLS;
  float* dst = thd + (size_t)b * CELLS;
  for (int f = t; f < 64 * 192; f += 256) {
    const int r = f / 192, c = f % 192;
    lds[f] = src[((i0 + r) * Mc + j0) * 3 + c];
  }
  __syncthreads();
  const int g = t >> 6, w = t & 63;
  for (int ld = g; ld < 127; ld += 4) {
    const int d = i0 + j0 + ld;
    const int ljlo = ld > 63 ? ld - 63 : 0;
    const int ljhi = ld < 63 ? ld : 63;
    const int L = (ljhi - ljlo + 1) * 3;
    const int base = (offd(d) + (j0 + ljlo) - lod(d)) * 3;
    for (int e = w; e < L; e += 64) {
      const int lj = ljlo + e / 3, s = e - (e / 3) * 3;
      dst[base + e] = lds[(ld - lj) * 192 + lj * 3 + s];
    }
  }
}

// 6 named scalars per pipeline slot (2 cols x 3 states)
#define DECL6(p) float p##0, p##1, p##2, p##3, p##4, p##5

// ---------------------------------------------------------------------------
// K2: forward wavefront. One wave per batch; lane l owns cols jA=2l, jB=2l+1.
// Exp-published cells: (m, w_k = e^{c_k-m}); LSE_k(c_k + A[k,s]) =
// m + log(sum_k w_k E[k][s]). Neighbor via __shfl_up. Loads/stores diag-major
// (contiguous across lanes). alpha -> ws; logZ[b] -> ws tail.
// ---------------------------------------------------------------------------

#define F2LOAD(P, dd) do {                                                     \
    const int dc_ = (dd) > 254 ? 254 : (dd);                                   \
    const float* p_ = thd + (size_t)(offd(dc_) + jA - lod(dc_)) * 3;           \
    P##0 = p_[0]; P##1 = p_[1]; P##2 = p_[2];                                  \
    P##3 = p_[3]; P##4 = p_[4]; P##5 = p_[5];                                  \
  } while (0)

#define F2STEP(P, dd) do {                                                     \
    const int iA_ = (dd) - jA, iB_ = (dd) - jB;                                \
    const int base_ = (offd(dd) + jA - lod(dd)) * 3;                           \
    float g0 = mS2 + __logf(wS20 * E00 + wS21 * E10 + wS22 * E20);             \
    float g1 = mPA + __logf(wPA0 * E01 + wPA1 * E11 + wPA2 * E21);             \
    float g2 = mS1 + __logf(wS10 * E02 + wS11 * E12 + wS12 * E22);             \
    if ((dd) == 0 && l == 0) g0 = 0.0f; /* origin: lse_m := 0 at (0,0) */      \
    float cA0 = HNEG, cA1 = HNEG, cA2 = HNEG;                                  \
    if ((unsigned)iA_ < (unsigned)Nc) {                                        \
      cA0 = P##0 + g0; cA1 = P##1 + g1; cA2 = P##2 + g2;                       \
      ad[base_ + 0] = cA0; ad[base_ + 1] = cA1; ad[base_ + 2] = cA2;           \
    }                                                                          \
    float h0 = mPP + __logf(wPP0 * E00 + wPP1 * E10 + wPP2 * E20);             \
    float h1 = mPB + __logf(wPB0 * E01 + wPB1 * E11 + wPB2 * E21);             \
    float h2 = mPA + __logf(wPA0 * E02 + wPA1 * E12 + wPA2 * E22);             \
    float cB0 = HNEG, cB1 = HNEG, cB2 = HNEG;                                  \
    if ((unsigned)iB_ < (unsigned)Nc) {                                        \
      cB0 = P##3 + h0; cB1 = P##4 + h1; cB2 = P##5 + h2;                       \
      ad[base_ + 3] = cB0; ad[base_ + 4] = cB1; ad[base_ + 5] = cB2;           \
    }                                                                          \
    if ((dd) == 254) { fz0 = cB0; fz1 = cB1; fz2 = cB2; }                      \
    const float mA_ = fmaxf(fmaxf(cA0, cA1), cA2);                             \
    const float a0_ = __expf(cA0 - mA_), a1_ = __expf(cA1 - mA_),              \
                a2_ = __expf(cA2 - mA_);                                       \
    const float mB_ = fmaxf(fmaxf(cB0, cB1), cB2);                             \
    const float b0_ = __expf(cB0 - mB_), b1_ = __expf(cB1 - mB_),              \
                b2_ = __expf(cB2 - mB_);                                       \
    mPP = mPA; wPP0 = wPA0; wPP1 = wPA1; wPP2 = wPA2;                          \
    mPA = mA_; wPA0 = a0_; wPA1 = a1_; wPA2 = a2_;                             \
    mPB = mB_; wPB0 = b0_; wPB1 = b1_; wPB2 = b2_;                             \
    mS2 = mS1; wS20 = wS10; wS21 = wS11; wS22 = wS12;                          \
    mS1 = __shfl_up(mB_, 1);                                                   \
    wS10 = __shfl_up(b0_, 1); wS11 = __shfl_up(b1_, 1);                        \
    wS12 = __shfl_up(b2_, 1);                                                  \
    if (l == 0) { mS1 = HNEG; wS10 = 1.f; wS11 = 1.f; wS12 = 1.f; }            \
  } while (0)

__global__ __launch_bounds__(64, 1) void fwd2_kernel(
    const float* __restrict__ thd_, const float* __restrict__ A,
    float* __restrict__ ad_, float* __restrict__ logZ_ws) {
  const int b = blockIdx.x;
  const int l = threadIdx.x;
  const float* thd = thd_ + (size_t)b * CELLS;
  float* ad = ad_ + (size_t)b * CELLS;
  const float* Ab = A + b * 9;
  const float E00 = __expf(Ab[0]), E01 = __expf(Ab[1]), E02 = __expf(Ab[2]);
  const float E10 = __expf(Ab[3]), E11 = __expf(Ab[4]), E12 = __expf(Ab[5]);
  const float E20 = __expf(Ab[6]), E21 = __expf(Ab[7]), E22 = __expf(Ab[8]);

  const int jA = 2 * l, jB = 2 * l + 1;

  float mPA = HNEG, wPA0 = 1.f, wPA1 = 1.f, wPA2 = 1.f;
  float mPB = HNEG, wPB0 = 1.f, wPB1 = 1.f, wPB2 = 1.f;
  float mPP = HNEG, wPP0 = 1.f, wPP1 = 1.f, wPP2 = 1.f;
  float mS1 = HNEG, wS10 = 1.f, wS11 = 1.f, wS12 = 1.f;
  float mS2 = HNEG, wS20 = 1.f, wS21 = 1.f, wS22 = 1.f;
  float fz0 = HNEG, fz1 = HNEG, fz2 = HNEG;

  DECL6(xt0); DECL6(xt1); DECL6(xt2); DECL6(xt3);
  DECL6(yt0); DECL6(yt1); DECL6(yt2); DECL6(yt3);

  F2LOAD(xt0, 0); F2LOAD(xt1, 1); F2LOAD(xt2, 2); F2LOAD(xt3, 3);
  F2LOAD(yt0, 4); F2LOAD(yt1, 5); F2LOAD(yt2, 6); F2LOAD(yt3, 7);

  for (int t = 0; t < 32; ++t) {
    const int d0 = 8 * t;
    F2STEP(xt0, d0 + 0); F2STEP(xt1, d0 + 1); F2STEP(xt2, d0 + 2); F2STEP(xt3, d0 + 3);
    F2LOAD(xt0, d0 + 8); F2LOAD(xt1, d0 + 9); F2LOAD(xt2, d0 + 10); F2LOAD(xt3, d0 + 11);
    F2STEP(yt0, d0 + 4); F2STEP(yt1, d0 + 5); F2STEP(yt2, d0 + 6); F2STEP(yt3, d0 + 7);
    F2LOAD(yt0, d0 + 12); F2LOAD(yt1, d0 + 13); F2LOAD(yt2, d0 + 14); F2LOAD(yt3, d0 + 15);
  }
  if (l == 63) logZ_ws[b] = lse3(fz0, fz1, fz2);
}

// ---------------------------------------------------------------------------
// K3: backward wavefront + combine. Flipped grid (p=N-1-i, q=M-1-j),
// u = g + theta_f; v = [u(p-1,q-1,0), u(p-1,q,1), u(p,q-1,2)];
// g_s = mv + log(sum_k e^{v_k-mv} E[s][k]); g=0 at flipped origin.
// Flipped diag dd maps to orig diag dor = 254-dd; theta/alpha read diag-major
// (contiguous), out = alpha + g - logZ written row-major (scattered stores).
// ---------------------------------------------------------------------------

#define B2LOAD(Pt, Pa, dd) do {                                                \
    int dor_ = 254 - (dd); if (dor_ < 0) dor_ = 0;                             \
    const int base_ = (offd(dor_) + jjB - lod(dor_)) * 3;                      \
    const float* p_ = thd + base_;                                             \
    Pt##3 = p_[0]; Pt##4 = p_[1]; Pt##5 = p_[2];                               \
    Pt##0 = p_[3]; Pt##1 = p_[4]; Pt##2 = p_[5];                               \
    const float* q_ = ad + base_;                                              \
    Pa##3 = q_[0]; Pa##4 = q_[1]; Pa##5 = q_[2];                               \
    Pa##0 = q_[3]; Pa##1 = q_[4]; Pa##2 = q_[5];                               \
  } while (0)

#define B2STEP(Pt, Pa, dd) do {                                                \
    const int iA_ = Nc - 1 - (dd) + jA;                                        \
    const int iB_ = Nc - 1 - (dd) + jB;                                        \
    float uA0 = HNEG, uA1 = HNEG, uA2 = HNEG;                                  \
    {                                                                          \
      const float v0 = S2u0, v1 = pAu1, v2 = S1u2;                             \
      const float mv = fmaxf(fmaxf(v0, v1), v2);                               \
      const float w0 = __expf(v0 - mv), w1 = __expf(v1 - mv),                  \
                  w2 = __expf(v2 - mv);                                        \
      float g0 = mv + __logf(w0 * E00 + w1 * E01 + w2 * E02);                  \
      float g1 = mv + __logf(w0 * E10 + w1 * E11 + w2 * E12);                  \
      float g2 = mv + __logf(w0 * E20 + w1 * E21 + w2 * E22);                  \
      if ((dd) == 0 && l == 0) { g0 = 0.f; g1 = 0.f; g2 = 0.f; }               \
      if ((unsigned)iA_ < (unsigned)Nc) {                                      \
        uA0 = g0 + Pt##0; uA1 = g1 + Pt##1; uA2 = g2 + Pt##2;                  \
        float* o_ = ob + (iA_ * Mc + jjA) * 3;                                 \
        o_[0] = Pa##0 + g0 - logZ;                                             \
        o_[1] = Pa##1 + g1 - logZ;                                             \
        o_[2] = Pa##2 + g2 - logZ;                                             \
      }                                                                        \
    }                                                                          \
    float uB0 = HNEG, uB1 = HNEG, uB2 = HNEG;                                  \
    {                                                                          \
      const float v0 = ppAu0, v1 = pBu1, v2 = pAu2;                            \
      const float mv = fmaxf(fmaxf(v0, v1), v2);                               \
      const float w0 = __expf(v0 - mv), w1 = __expf(v1 - mv),                  \
                  w2 = __expf(v2 - mv);                                        \
      const float g0 = mv + __logf(w0 * E00 + w1 * E01 + w2 * E02);            \
      const float g1 = mv + __logf(w0 * E10 + w1 * E11 + w2 * E12);            \
      const float g2 = mv + __logf(w0 * E20 + w1 * E21 + w2 * E22);            \
      if ((unsigned)iB_ < (unsigned)Nc) {                                      \
        uB0 = g0 + Pt##3; uB1 = g1 + Pt##4; uB2 = g2 + Pt##5;                  \
        float* o_ = ob + (iB_ * Mc + jjB) * 3;                                 \
        o_[0] = Pa##3 + g0 - logZ;                                             \
        o_[1] = Pa##4 + g1 - logZ;                                             \
        o_[2] = Pa##5 + g2 - logZ;                                             \
      }                                                                        \
    }                                                                          \
    ppAu0 = pAu0; pAu0 = uA0; pAu1 = uA1; pAu2 = uA2; pBu1 = uB1;              \
    S2u0 = S1u0;                                                               \
    S1u0 = __shfl_up(uB0, 1);                                                  \
    S1u2 = __shfl_up(uB2, 1);                                                  \
    if (l == 0) { S1u0 = HNEG; S1u2 = HNEG; }                                  \
  } while (0)

__global__ __launch_bounds__(64, 1) void bwd2_kernel(
    const float* __restrict__ thd_, const float* __restrict__ A,
    const float* __restrict__ ad_, const float* __restrict__ logZ_ws,
    float* __restrict__ ob_) {
  const int b = blockIdx.x;
  const int l = threadIdx.x;
  const float* thd = thd_ + (size_t)b * CELLS;
  const float* ad = ad_ + (size_t)b * CELLS;
  float* ob = ob_ + (size_t)b * CELLS;
  const float* Ab = A + b * 9;
  const float E00 = __expf(Ab[0]), E01 = __expf(Ab[1]), E02 = __expf(Ab[2]);
  const float E10 = __expf(Ab[3]), E11 = __expf(Ab[4]), E12 = __expf(Ab[5]);
  const float E20 = __expf(Ab[6]), E21 = __expf(Ab[7]), E22 = __expf(Ab[8]);

  const int jA = 2 * l, jB = 2 * l + 1;            // flipped cols q
  const int jjA = Mc - 1 - jA, jjB = Mc - 1 - jB;  // orig cols

  const float logZ = logZ_ws[b];

  float pAu0 = HNEG, pAu1 = HNEG, pAu2 = HNEG;
  float ppAu0 = HNEG, pBu1 = HNEG;
  float S1u0 = HNEG, S1u2 = HNEG, S2u0 = HNEG;

  DECL6(xt0); DECL6(xt1); DECL6(xt2); DECL6(xt3);
  DECL6(yt0); DECL6(yt1); DECL6(yt2); DECL6(yt3);
  DECL6(xa0); DECL6(xa1); DECL6(xa2); DECL6(xa3);
  DECL6(ya0); DECL6(ya1); DECL6(ya2); DECL6(ya3);

  B2LOAD(xt0, xa0, 0); B2LOAD(xt1, xa1, 1); B2LOAD(xt2, xa2, 2); B2LOAD(xt3, xa3, 3);
  B2LOAD(yt0, ya0, 4); B2LOAD(yt1, ya1, 5); B2LOAD(yt2, ya2, 6); B2LOAD(yt3, ya3, 7);

  for (int t = 0; t < 32; ++t) {
    const int d0 = 8 * t;
    B2STEP(xt0, xa0, d0 + 0); B2STEP(xt1, xa1, d0 + 1);
    B2STEP(xt2, xa2, d0 + 2); B2STEP(xt3, xa3, d0 + 3);
    B2LOAD(xt0, xa0, d0 + 8); B2LOAD(xt1, xa1, d0 + 9);
    B2LOAD(xt2, xa2, d0 + 10); B2LOAD(xt3, xa3, d0 + 11);
    B2STEP(yt0, ya0, d0 + 4); B2STEP(yt1, ya1, d0 + 5);
    B2STEP(yt2, ya2, d0 + 6); B2STEP(yt3, ya3, d0 + 7);
    B2LOAD(yt0, ya0, d0 + 12); B2LOAD(yt1, ya1, d0 + 13);
    B2LOAD(yt2, ya2, d0 + 14); B2LOAD(yt3, ya3, d0 + 15);
  }
}

// ---------------------------------------------------------------------------
// Fallback (round-2 structure, known-correct ~355 us): used only if ws small.
// ---------------------------------------------------------------------------
__global__ __launch_bounds__(128) void fwd_fb(const float* __restrict__ theta,
                                              const float* __restrict__ A,
                                              float* __restrict__ out) {
  const int b = blockIdx.x;
  const int j = threadIdx.x;
  const float* th = theta + (size_t)b * CELLS;
  float* ob = out + (size_t)b * CELLS;

  __shared__ float sA[9];
  __shared__ float ring[3][Mc + 1][3];
  if (j < 9) sA[j] = A[b * 9 + j];
  {
    float* rf = &ring[0][0][0];
    for (int t = j; t < 3 * (Mc + 1) * 3; t += Mc) rf[t] = HNEG;
  }
  __syncthreads();
  const float A00 = sA[0], A01 = sA[1], A02 = sA[2];
  const float A10 = sA[3], A11 = sA[4], A12 = sA[5];
  const float A20 = sA[6], A21 = sA[7], A22 = sA[8];

  float p0 = HNEG, p1 = HNEG, p2 = HNEG;
  float tc0 = 0.f, tc1 = 0.f, tc2 = 0.f, tn0 = 0.f, tn1 = 0.f, tn2 = 0.f;
  if (j == 0) { tc0 = th[0]; tc1 = th[1]; tc2 = th[2]; }
  if (j <= 1) {
    const int i1 = 1 - j;
    const float* p = th + (i1 * Mc + j) * 3;
    tn0 = p[0]; tn1 = p[1]; tn2 = p[2];
  }
  int s0 = 0, s1 = 2, s2 = 1;
  for (int d = 0; d < Nc + Mc - 1; ++d) {
    const int i = d - j;
    float tf0 = 0.f, tf1 = 0.f, tf2 = 0.f;
    const int ip = i + 2;
    if (ip >= 0 && ip < Nc) {
      const float* p = th + (ip * Mc + j) * 3;
      tf0 = p[0]; tf1 = p[1]; tf2 = p[2];
    }
    float c0 = HNEG, c1 = HNEG, c2 = HNEG;
    if (i >= 0 && i < Nc) {
      const float* nd1 = ring[s1][j];
      const float* nd2 = ring[s2][j];
      float lm = lse3(nd2[0] + A00, nd2[1] + A10, nd2[2] + A20);
      if (i == 0 && j == 0) lm = 0.0f;
      float lx = lse3(p0 + A01, p1 + A11, p2 + A21);
      float ly = lse3(nd1[0] + A02, nd1[1] + A12, nd1[2] + A22);
      c0 = tc0 + lm; c1 = tc1 + lx; c2 = tc2 + ly;
      float* o = ob + (i * Mc + j) * 3;
      o[0] = c0; o[1] = c1; o[2] = c2;
    }
    float* w = ring[s0][j + 1];
    w[0] = c0; w[1] = c1; w[2] = c2;
    __syncthreads();
    p0 = c0; p1 = c1; p2 = c2;
    tc0 = tn0; tc1 = tn1; tc2 = tn2;
    tn0 = tf0; tn1 = tf1; tn2 = tf2;
    const int t = s2; s2 = s1; s1 = s0; s0 = t;
  }
}

__global__ __launch_bounds__(128) void bwd_fb(const float* __restrict__ theta,
                                              const float* __restrict__ A,
                                              float* __restrict__ ob_) {
  const int b = blockIdx.x;
  const int q = threadIdx.x;
  const float* th = theta + (size_t)b * CELLS;
  float* ob = ob_ + (size_t)b * CELLS;

  __shared__ float sA[9];
  __shared__ float ring[3][Mc + 1][3];
  __shared__ float sZ;
  if (q < 9) sA[q] = A[b * 9 + q];
  {
    float* rf = &ring[0][0][0];
    for (int t = q; t < 3 * (Mc + 1) * 3; t += Mc) rf[t] = HNEG;
  }
  if (q == 0) {
    sZ = lse3(ob[(Nc * Mc - 1) * 3 + 0], ob[(Nc * Mc - 1) * 3 + 1],
              ob[(Nc * Mc - 1) * 3 + 2]);
  }
  __syncthreads();
  const float A00 = sA[0], A01 = sA[1], A02 = sA[2];
  const float A10 = sA[3], A11 = sA[4], A12 = sA[5];
  const float A20 = sA[6], A21 = sA[7], A22 = sA[8];
  const float logZ = sZ;

  const int jj = Mc - 1 - q;
  float pu1 = HNEG;
  float tc0 = 0.f, tc1 = 0.f, tc2 = 0.f, tn0 = 0.f, tn1 = 0.f, tn2 = 0.f;
  float ac0 = 0.f, ac1 = 0.f, ac2 = 0.f, an0 = 0.f, an1 = 0.f, an2 = 0.f;
  if (q == 0) {
    const float* p = th + ((Nc - 1) * Mc + jj) * 3;
    tc0 = p[0]; tc1 = p[1]; tc2 = p[2];
    const float* a = ob + ((Nc - 1) * Mc + jj) * 3;
    ac0 = a[0]; ac1 = a[1]; ac2 = a[2];
  }
  if (q <= 1) {
    const int i1 = Nc - 2 + q;
    const float* p = th + (i1 * Mc + jj) * 3;
    tn0 = p[0]; tn1 = p[1]; tn2 = p[2];
    const float* a = ob + (i1 * Mc + jj) * 3;
    an0 = a[0]; an1 = a[1]; an2 = a[2];
  }
  int s0 = 0, s1 = 2, s2 = 1;
  for (int d = 0; d < Nc + Mc - 1; ++d) {
    const int p = d - q;
    const int i = Nc - 1 - p;
    float tf0 = 0.f, tf1 = 0.f, tf2 = 0.f, af0 = 0.f, af1 = 0.f, af2 = 0.f;
    const int ipf = i - 2;
    if (ipf >= 0 && ipf < Nc) {
      const float* pp = th + (ipf * Mc + jj) * 3;
      tf0 = pp[0]; tf1 = pp[1]; tf2 = pp[2];
      const float* aa = ob + (ipf * Mc + jj) * 3;
      af0 = aa[0]; af1 = aa[1]; af2 = aa[2];
    }
    float u0 = HNEG, u1 = HNEG, u2 = HNEG;
    if (p >= 0 && p < Nc) {
      const float* nd1 = ring[s1][q];
      const float* nd2 = ring[s2][q];
      const float v0 = nd2[0];
      const float v1 = pu1;
      const float v2 = nd1[2];
      float g0 = lse3(A00 + v0, A01 + v1, A02 + v2);
      float g1 = lse3(A10 + v0, A11 + v1, A12 + v2);
      float g2 = lse3(A20 + v0, A21 + v1, A22 + v2);
      if (p == 0 && q == 0) { g0 = 0.0f; g1 = 0.0f; g2 = 0.0f; }
      u0 = g0 + tc0; u1 = g1 + tc1; u2 = g2 + tc2;
      float* o = ob + (i * Mc + jj) * 3;
      o[0] = ac0 + g0 - logZ;
      o[1] = ac1 + g1 - logZ;
      o[2] = ac2 + g2 - logZ;
    }
    float* w = ring[s0][q + 1];
    w[0] = u0; w[1] = u1; w[2] = u2;
    __syncthreads();
    pu1 = u1;
    tc0 = tn0; tc1 = tn1; tc2 = tn2;
    tn0 = tf0; tn1 = tf1; tn2 = tf2;
    ac0 = an0; ac1 = an1; ac2 = an2;
    an0 = af0; an1 = af1; an2 = af2;
    const int t = s2; s2 = s1; s1 = s0; s0 = t;
  }
}

extern "C" void kernel_launch(void* const* d_in, const int* in_sizes, int n_in,
                              void* d_out, int out_size, void* d_ws, size_t ws_size,
                              hipStream_t stream) {
  const float* theta = (const float*)d_in[0];
  const float* A = (const float*)d_in[1];
  float* out = (float*)d_out;
  const int B = in_sizes[1] / 9;  // A is (B, 3, 3)

  const size_t need = (size_t)B * CELLS * 8 + (size_t)B * 4;  // thd + ad + logZ
  if (ws_size >= need) {
    float* thd = (float*)d_ws;
    float* ad = thd + (size_t)B * CELLS;
    float* logZ_ws = ad + (size_t)B * CELLS;
    transpose_kernel<<<dim3(B, 4), dim3(256), 0, stream>>>(theta, thd);
    fwd2_kernel<<<dim3(B), dim3(64), 0, stream>>>(thd, A, ad, logZ_ws);
    bwd2_kernel<<<dim3(B), dim3(64), 0, stream>>>(thd, A, ad, logZ_ws, out);
  } else {
    fwd_fb<<<dim3(B), dim3(128), 0, stream>>>(theta, A, out);
    bwd_fb<<<dim3(B), dim3(128), 0, stream>>>(theta, A, out);
  }
}